// Round 3
// baseline (8838.844 us; speedup 1.0000x reference)
//
#include <hip/hip_runtime.h>
#include <hip/hip_bf16.h>
#include <cstdint>

#define BATCH 4096
#define DIM   512
#define HID   1024
#define TSTEPS 20
#define NBLK  256
#define NTHR  512

typedef unsigned short u16;
typedef short s16x8 __attribute__((ext_vector_type(8)));
typedef float f32x4 __attribute__((ext_vector_type(4)));

__device__ __forceinline__ u16 f2bf(float f) {
    unsigned int u = __float_as_uint(f);
    u = (u + 0x7FFFu + ((u >> 16) & 1u)) >> 16;   // RNE
    return (u16)u;
}

__device__ __forceinline__ float fast_tanh(float x) {
    float ax = __builtin_fabsf(x);
    float e  = __expf(2.0f * ax);                 // inf for large ax -> t = 1
    float t  = 1.0f - 2.0f * __builtin_amdgcn_rcpf(e + 1.0f);
    return __builtin_copysignf(t, x);
}

__global__ void zero_cnt(unsigned* cnt) { cnt[0] = 0u; }

// monotone-counter grid barrier; all NBLK blocks guaranteed co-resident (1 block/CU).
__device__ __forceinline__ void grid_barrier(unsigned* cnt, unsigned target) {
    __syncthreads();
    if (threadIdx.x == 0) {
        __hip_atomic_fetch_add(cnt, 1u, __ATOMIC_RELEASE, __HIP_MEMORY_SCOPE_AGENT);
        unsigned v;
        do {
            __builtin_amdgcn_s_sleep(2);
            v = __hip_atomic_load(cnt, __ATOMIC_RELAXED, __HIP_MEMORY_SCOPE_AGENT);
        } while (v < target);
    }
    __syncthreads();
    __builtin_amdgcn_fence(__ATOMIC_ACQUIRE, "agent");
}

__global__ __launch_bounds__(NTHR, 2) void ode_persistent(
    const float* __restrict__ x0, const float* __restrict__ tgrid,
    const float* __restrict__ W1, const float* __restrict__ b1,
    const float* __restrict__ W2, const float* __restrict__ b2,
    float* __restrict__ out, u16* __restrict__ ybf, u16* __restrict__ act,
    float* __restrict__ accum, unsigned* __restrict__ cnt)
{
    __shared__ u16 w1s[64 * 512];    // 64 KiB: W1^T slice [64 cols][512 k], XOR-swizzled
    __shared__ u16 w2s[32 * 1024];   // 64 KiB: W2^T slice [32 cols][1024 k], XOR-swizzled

    const int tid  = threadIdx.x;
    const int lane = tid & 63;
    const int wid  = tid >> 6;            // 0..7
    const int bid  = blockIdx.x;
    const int xcd  = bid & 7;             // presumed XCD (perf-only heuristic)
    const int sl   = bid >> 3;            // 0..31
    const int mt   = xcd * 2 + (sl >> 4); // 0..15  M-strip (256 rows)
    const int nt   = sl & 15;             // 0..15  N-tile (both phases)

    // ---- one-time: fill weight slices into LDS (coalesced global, swizzled ds_write) ----
    for (int i = tid; i < 64 * 512; i += NTHR) {
        int c = i & 63, k = i >> 6;
        unsigned byte = ((unsigned)(c * 1024 + k * 2)) ^ ((unsigned)(c & 7) << 4);
        *(u16*)((char*)w1s + byte) = f2bf(W1[(size_t)k * HID + nt * 64 + c]);
    }
    for (int i = tid; i < 32 * 1024; i += NTHR) {
        int c = i & 31, k = i >> 5;
        unsigned byte = ((unsigned)(c * 2048 + k * 2)) ^ ((unsigned)(c & 7) << 4);
        *(u16*)((char*)w2s + byte) = f2bf(W2[(size_t)k * DIM + nt * 32 + c]);
    }

    // ---- one-time: out[0] = x0 ; ybf = bf16(x0) ----
    for (int i = bid * NTHR + tid; i < BATCH * DIM; i += NBLK * NTHR) {
        float v = x0[i];
        out[i] = v;
        ybf[i] = f2bf(v);
    }
    __syncthreads();

    unsigned phase = 1;
    grid_barrier(cnt, phase * NBLK); ++phase;

    const int grow0 = mt * 256 + wid * 32;     // wave's first global row

#pragma clang loop unroll(disable)
    for (int ev = 0; ev < 4 * (TSTEPS - 1); ++ev) {
        const int s  = ev >> 2;
        const int st = ev & 3;

        // ================= phase 1: h = tanh(y @ W1 + b1) -> act =================
        {
            const u16* pa0 = ybf + (size_t)(grow0 + (lane & 15)) * DIM + (lane >> 4) * 8;
            const u16* pa1 = pa0 + 16 * DIM;
            f32x4 acc[2][4];
#pragma unroll
            for (int mf = 0; mf < 2; ++mf)
#pragma unroll
                for (int nf = 0; nf < 4; ++nf)
                    acc[mf][nf] = (f32x4){0.f, 0.f, 0.f, 0.f};

#pragma unroll
            for (int kt = 0; kt < DIM / 32; ++kt) {
                s16x8 a0 = *(const s16x8*)(pa0 + kt * 32);
                s16x8 a1 = *(const s16x8*)(pa1 + kt * 32);
                s16x8 bfrag[4];
#pragma unroll
                for (int nf = 0; nf < 4; ++nf) {
                    int c = nf * 16 + (lane & 15);
                    unsigned k = (unsigned)(kt * 32 + (lane >> 4) * 8);
                    unsigned byte = ((unsigned)(c * 1024) + k * 2) ^ ((unsigned)(c & 7) << 4);
                    bfrag[nf] = *(const s16x8*)((const char*)w1s + byte);
                }
#pragma unroll
                for (int nf = 0; nf < 4; ++nf) {
                    acc[0][nf] = __builtin_amdgcn_mfma_f32_16x16x32_bf16(a0, bfrag[nf], acc[0][nf], 0, 0, 0);
                    acc[1][nf] = __builtin_amdgcn_mfma_f32_16x16x32_bf16(a1, bfrag[nf], acc[1][nf], 0, 0, 0);
                }
            }
#pragma unroll
            for (int mf = 0; mf < 2; ++mf)
#pragma unroll
                for (int nf = 0; nf < 4; ++nf) {
                    int col = nt * 64 + nf * 16 + (lane & 15);
                    float bv = b1[col];
#pragma unroll
                    for (int j = 0; j < 4; ++j) {
                        int grow = grow0 + mf * 16 + (lane >> 4) * 4 + j;
                        act[(size_t)grow * HID + col] = f2bf(fast_tanh(acc[mf][nf][j] + bv));
                    }
                }
        }
        grid_barrier(cnt, phase * NBLK); ++phase;

        // ================= phase 2: k = act @ W2 + b2 ; RK4 epilogue =================
        {
            const u16* pa0 = act + (size_t)(grow0 + (lane & 15)) * HID + (lane >> 4) * 8;
            const u16* pa1 = pa0 + 16 * HID;
            f32x4 acc[2][2];
#pragma unroll
            for (int mf = 0; mf < 2; ++mf)
#pragma unroll
                for (int nf = 0; nf < 2; ++nf)
                    acc[mf][nf] = (f32x4){0.f, 0.f, 0.f, 0.f};

#pragma unroll
            for (int kt = 0; kt < HID / 32; ++kt) {
                s16x8 a0 = *(const s16x8*)(pa0 + kt * 32);
                s16x8 a1 = *(const s16x8*)(pa1 + kt * 32);
                s16x8 bfrag[2];
#pragma unroll
                for (int nf = 0; nf < 2; ++nf) {
                    int c = nf * 16 + (lane & 15);
                    unsigned k = (unsigned)(kt * 32 + (lane >> 4) * 8);
                    unsigned byte = ((unsigned)(c * 2048) + k * 2) ^ ((unsigned)(c & 7) << 4);
                    bfrag[nf] = *(const s16x8*)((const char*)w2s + byte);
                }
#pragma unroll
                for (int nf = 0; nf < 2; ++nf) {
                    acc[0][nf] = __builtin_amdgcn_mfma_f32_16x16x32_bf16(a0, bfrag[nf], acc[0][nf], 0, 0, 0);
                    acc[1][nf] = __builtin_amdgcn_mfma_f32_16x16x32_bf16(a1, bfrag[nf], acc[1][nf], 0, 0, 0);
                }
            }

            const float dtv = tgrid[s + 1] - tgrid[s];
            const float* yb = out + (size_t)s * BATCH * DIM;
            float*       yn = out + (size_t)(s + 1) * BATCH * DIM;
#pragma unroll
            for (int mf = 0; mf < 2; ++mf)
#pragma unroll
                for (int nf = 0; nf < 2; ++nf) {
                    int col = nt * 32 + nf * 16 + (lane & 15);
                    float bv = b2[col];
#pragma unroll
                    for (int j = 0; j < 4; ++j) {
                        int grow = grow0 + mf * 16 + (lane >> 4) * 4 + j;
                        size_t idx = (size_t)grow * DIM + col;
                        float v = acc[mf][nf][j] + bv;
                        float ybase = yb[idx];
                        if (st == 0) {
                            accum[idx] = v;
                            ybf[idx] = f2bf(ybase + 0.5f * dtv * v);
                        } else if (st == 1) {
                            accum[idx] += 2.0f * v;
                            ybf[idx] = f2bf(ybase + 0.5f * dtv * v);
                        } else if (st == 2) {
                            accum[idx] += 2.0f * v;
                            ybf[idx] = f2bf(ybase + dtv * v);
                        } else {
                            float y1 = ybase + (dtv * (1.0f / 6.0f)) * (accum[idx] + v);
                            yn[idx] = y1;
                            ybf[idx] = f2bf(y1);
                        }
                    }
                }
        }
        grid_barrier(cnt, phase * NBLK); ++phase;
    }
}

extern "C" void kernel_launch(void* const* d_in, const int* in_sizes, int n_in,
                              void* d_out, int out_size, void* d_ws, size_t ws_size,
                              hipStream_t stream) {
    (void)in_sizes; (void)n_in; (void)out_size; (void)ws_size;
    const float* x0 = (const float*)d_in[0];
    const float* t  = (const float*)d_in[1];
    const float* W1 = (const float*)d_in[2];
    const float* b1 = (const float*)d_in[3];
    const float* W2 = (const float*)d_in[4];
    const float* b2 = (const float*)d_in[5];
    float* out = (float*)d_out;

    char* ws = (char*)d_ws;
    u16*      ybf   = (u16*)     (ws);               //  4 MB [4096,512]  bf16
    u16*      act   = (u16*)     (ws + (4u  << 20)); //  8 MB [4096,1024] bf16
    float*    accum = (float*)   (ws + (12u << 20)); //  8 MB [4096,512]  f32
    unsigned* cnt   = (unsigned*)(ws + (20u << 20)); //  barrier counter

    zero_cnt<<<1, 1, 0, stream>>>(cnt);
    ode_persistent<<<NBLK, NTHR, 0, stream>>>(x0, t, W1, b1, W2, b2,
                                              out, ybf, act, accum, cnt);
}

// Round 4
// 6736.150 us; speedup vs baseline: 1.3122x; 1.3122x over previous
//
#include <hip/hip_runtime.h>
#include <hip/hip_bf16.h>
#include <cstdint>

#define BATCH 4096
#define DIM   512
#define HID   1024
#define TSTEPS 20
#define NBLK  256
#define NTHR  512

typedef unsigned short u16;
typedef short s16x8 __attribute__((ext_vector_type(8)));
typedef float f32x4 __attribute__((ext_vector_type(4)));

__device__ __forceinline__ u16 f2bf(float f) {
    unsigned int u = __float_as_uint(f);
    u = (u + 0x7FFFu + ((u >> 16) & 1u)) >> 16;   // RNE
    return (u16)u;
}

__device__ __forceinline__ float fast_tanh(float x) {
    float ax = __builtin_fabsf(x);
    float e  = __expf(2.0f * ax);                 // inf for large ax -> t = 1
    float t  = 1.0f - 2.0f * __builtin_amdgcn_rcpf(e + 1.0f);
    return __builtin_copysignf(t, x);
}

__global__ void zero_cnt(unsigned* cnt) { cnt[0] = 0u; }

// monotone-counter grid barrier; all NBLK blocks co-resident (1 block/CU, 128KB LDS).
__device__ __forceinline__ void grid_barrier(unsigned* cnt, unsigned target) {
    __syncthreads();
    if (threadIdx.x == 0) {
        __hip_atomic_fetch_add(cnt, 1u, __ATOMIC_RELEASE, __HIP_MEMORY_SCOPE_AGENT);
        unsigned v;
        do {
            __builtin_amdgcn_s_sleep(2);
            v = __hip_atomic_load(cnt, __ATOMIC_RELAXED, __HIP_MEMORY_SCOPE_AGENT);
        } while (v < target);
    }
    __syncthreads();
    __builtin_amdgcn_fence(__ATOMIC_ACQUIRE, "agent");
}

// Weight LDS layout: per (16-col x 32-k) fragment tile stored contiguously (1KB).
// Read = ds_read_b128 at tile*1024 + lane*16  -> conflict-free by construction.
// Within tile, element (c, k) lives at u16 index ((k>>3)&3)*128 + (c&15)*8 + (k&7).

__global__ __launch_bounds__(NTHR, 2) void ode_persistent(
    const float* __restrict__ x0, const float* __restrict__ tgrid,
    const float* __restrict__ W1, const float* __restrict__ b1,
    const float* __restrict__ W2, const float* __restrict__ b2,
    float* __restrict__ out, u16* __restrict__ ybf, u16* __restrict__ act,
    unsigned* __restrict__ cnt)
{
    __shared__ u16 w1s[64 * 512];    // 64 KiB: W1 slice, 64 frag-tiles (cg 0..3, ks 0..15)
    __shared__ u16 w2s[32 * 1024];   // 64 KiB: W2 slice, 64 frag-tiles (cg 0..1, ks 0..31)

    const int tid  = threadIdx.x;
    const int lane = tid & 63;
    const int w    = tid >> 6;            // 0..7
    const int bid  = blockIdx.x;
    const int xcd  = bid & 7;             // default round-robin XCD assignment
    const int sl   = bid >> 3;            // 0..31
    const int mt   = xcd * 2 + (sl & 1);  // 0..15  M-strip (256 rows), strip-mates share XCD
    const int nt   = sl >> 1;             // 0..15  N-slice

    // ---- one-time: weight slices -> LDS frag-tiles ----
    for (int idx = tid; idx < 64 * 512; idx += NTHR) {
        int c = idx & 63, k = idx >> 6;               // coalesced: 64 consecutive cols
        int tile = (c >> 4) * 16 + (k >> 5);
        int off = tile * 512 + (((k >> 3) & 3) * 16 + (c & 15)) * 8 + (k & 7);
        w1s[off] = f2bf(W1[(size_t)k * HID + nt * 64 + c]);
    }
    for (int idx = tid; idx < 32 * 1024; idx += NTHR) {
        int c = idx & 31, k = idx >> 5;
        int tile = (c >> 4) * 32 + (k >> 5);
        int off = tile * 512 + (((k >> 3) & 3) * 16 + (c & 15)) * 8 + (k & 7);
        w2s[off] = f2bf(W2[(size_t)k * DIM + nt * 32 + c]);
    }

    // ---- per-thread RK4 state in registers: block owns tile rows [mt*256+w*32, +32), cols [nt*32, +32) ----
    const int r0 = mt * 256 + w * 32;
    const int c0 = nt * 32;
    const int lr = (lane >> 4) * 4;
    const int lc = lane & 15;

    float ybase[2][2][4];   // carried across the whole integration
    float kacc[2][2][4];

#pragma unroll
    for (int rf = 0; rf < 2; ++rf)
#pragma unroll
        for (int cf = 0; cf < 2; ++cf)
#pragma unroll
            for (int j = 0; j < 4; ++j) {
                int row = r0 + rf * 16 + lr + j;
                int col = c0 + cf * 16 + lc;
                float v = x0[(size_t)row * DIM + col];
                ybase[rf][cf][j] = v;
                out[(size_t)row * DIM + col] = v;
                ybf[(size_t)row * DIM + col] = f2bf(v);
            }

    // hoisted biases (constant across evals)
    float bv1[4], bv2[2];
#pragma unroll
    for (int cg = 0; cg < 4; ++cg) bv1[cg] = b1[nt * 64 + cg * 16 + lc];
#pragma unroll
    for (int cg = 0; cg < 2; ++cg) bv2[cg] = b2[c0 + cg * 16 + lc];

    unsigned phase = 1;
    grid_barrier(cnt, phase * NBLK); ++phase;

    // per-lane global A base pointers (A-frag: lane&15 = row, lane>>4 = k-quad)
    const u16* a1base = ybf + (size_t)(r0 + lc) * DIM + (lane >> 4) * 8;
    const u16* a2base = act + (size_t)(r0 + lc) * HID + (lane >> 4) * 8;

#pragma clang loop unroll(disable)
    for (int ev = 0; ev < 4 * (TSTEPS - 1); ++ev) {
        const int s  = ev >> 2;
        const int st = ev & 3;

        // ========== phase 1: h = tanh(y @ W1 + b1) -> act   (wave tile 32r x 64c) ==========
        {
            f32x4 acc1[2][4];
#pragma unroll
            for (int rf = 0; rf < 2; ++rf)
#pragma unroll
                for (int cg = 0; cg < 4; ++cg)
                    acc1[rf][cg] = (f32x4){0.f, 0.f, 0.f, 0.f};

#pragma unroll
            for (int ksb = 0; ksb < 4; ++ksb) {          // batches of 4 K32-steps
                s16x8 a[4][2];
#pragma unroll
                for (int kk = 0; kk < 4; ++kk)           // 8 loads in flight
#pragma unroll
                    for (int rf = 0; rf < 2; ++rf)
                        a[kk][rf] = *(const s16x8*)(a1base + (size_t)rf * 16 * DIM + (ksb * 4 + kk) * 32);
#pragma unroll
                for (int kk = 0; kk < 4; ++kk) {
                    const int ks = ksb * 4 + kk;
                    s16x8 bf_[4];
#pragma unroll
                    for (int cg = 0; cg < 4; ++cg)
                        bf_[cg] = *(const s16x8*)&w1s[(cg * 16 + ks) * 512 + lane * 8];
#pragma unroll
                    for (int rf = 0; rf < 2; ++rf)
#pragma unroll
                        for (int cg = 0; cg < 4; ++cg)
                            acc1[rf][cg] = __builtin_amdgcn_mfma_f32_16x16x32_bf16(
                                a[kk][rf], bf_[cg], acc1[rf][cg], 0, 0, 0);
                }
            }
#pragma unroll
            for (int rf = 0; rf < 2; ++rf)
#pragma unroll
                for (int cg = 0; cg < 4; ++cg)
#pragma unroll
                    for (int j = 0; j < 4; ++j) {
                        int row = r0 + rf * 16 + lr + j;
                        int col = nt * 64 + cg * 16 + lc;
                        act[(size_t)row * HID + col] = f2bf(fast_tanh(acc1[rf][cg][j] + bv1[cg]));
                    }
        }
        grid_barrier(cnt, phase * NBLK); ++phase;

        // ========== phase 2: k = act @ W2 + b2 ; RK4 in regs   (wave tile 32r x 32c) ==========
        {
            f32x4 acc2[2][2];
#pragma unroll
            for (int rf = 0; rf < 2; ++rf)
#pragma unroll
                for (int cf = 0; cf < 2; ++cf)
                    acc2[rf][cf] = (f32x4){0.f, 0.f, 0.f, 0.f};

#pragma unroll
            for (int ksb = 0; ksb < 8; ++ksb) {
                s16x8 a[4][2];
#pragma unroll
                for (int kk = 0; kk < 4; ++kk)
#pragma unroll
                    for (int rf = 0; rf < 2; ++rf)
                        a[kk][rf] = *(const s16x8*)(a2base + (size_t)rf * 16 * HID + (ksb * 4 + kk) * 32);
#pragma unroll
                for (int kk = 0; kk < 4; ++kk) {
                    const int ks = ksb * 4 + kk;
                    s16x8 bf_[2];
#pragma unroll
                    for (int cf = 0; cf < 2; ++cf)
                        bf_[cf] = *(const s16x8*)&w2s[(cf * 32 + ks) * 512 + lane * 8];
#pragma unroll
                    for (int rf = 0; rf < 2; ++rf)
#pragma unroll
                        for (int cf = 0; cf < 2; ++cf)
                            acc2[rf][cf] = __builtin_amdgcn_mfma_f32_16x16x32_bf16(
                                a[kk][rf], bf_[cf], acc2[rf][cf], 0, 0, 0);
                }
            }

            const float dtv = tgrid[s + 1] - tgrid[s];
            float* yn = out + (size_t)(s + 1) * BATCH * DIM;
#pragma unroll
            for (int rf = 0; rf < 2; ++rf)
#pragma unroll
                for (int cf = 0; cf < 2; ++cf)
#pragma unroll
                    for (int j = 0; j < 4; ++j) {
                        int row = r0 + rf * 16 + lr + j;
                        int col = c0 + cf * 16 + lc;
                        size_t idx = (size_t)row * DIM + col;
                        float v = acc2[rf][cf][j] + bv2[cf];
                        if (st == 0) {
                            kacc[rf][cf][j] = v;
                            ybf[idx] = f2bf(ybase[rf][cf][j] + 0.5f * dtv * v);
                        } else if (st == 1) {
                            kacc[rf][cf][j] += 2.0f * v;
                            ybf[idx] = f2bf(ybase[rf][cf][j] + 0.5f * dtv * v);
                        } else if (st == 2) {
                            kacc[rf][cf][j] += 2.0f * v;
                            ybf[idx] = f2bf(ybase[rf][cf][j] + dtv * v);
                        } else {
                            float y1 = ybase[rf][cf][j] + (dtv * (1.0f / 6.0f)) * (kacc[rf][cf][j] + v);
                            yn[idx] = y1;
                            ybf[idx] = f2bf(y1);
                            ybase[rf][cf][j] = y1;   // carry to next step
                        }
                    }
        }
        grid_barrier(cnt, phase * NBLK); ++phase;
    }
}

extern "C" void kernel_launch(void* const* d_in, const int* in_sizes, int n_in,
                              void* d_out, int out_size, void* d_ws, size_t ws_size,
                              hipStream_t stream) {
    (void)in_sizes; (void)n_in; (void)out_size; (void)ws_size;
    const float* x0 = (const float*)d_in[0];
    const float* t  = (const float*)d_in[1];
    const float* W1 = (const float*)d_in[2];
    const float* b1 = (const float*)d_in[3];
    const float* W2 = (const float*)d_in[4];
    const float* b2 = (const float*)d_in[5];
    float* out = (float*)d_out;

    char* ws = (char*)d_ws;
    u16*      ybf = (u16*)     (ws);               //  4 MB [4096,512]  bf16
    u16*      act = (u16*)     (ws + (4u  << 20)); //  8 MB [4096,1024] bf16
    unsigned* cnt = (unsigned*)(ws + (12u << 20)); //  barrier counter

    zero_cnt<<<1, 1, 0, stream>>>(cnt);
    ode_persistent<<<NBLK, NTHR, 0, stream>>>(x0, t, W1, b1, W2, b2,
                                              out, ybf, act, cnt);
}